// Round 7
// baseline (99.675 us; speedup 1.0000x reference)
//
#include <hip/hip_runtime.h>
#include <cstdint>

typedef float f32x4 __attribute__((ext_vector_type(4)));

constexpr int Bv = 32;      // batch rows (M)
constexpr int Hv = 4096;    // hidden (K1, N2)
constexpr int Iv = 2048;    // intermediate
constexpr int N1 = 4096;    // 2*I

// ---------------------------------------------------------------------------
// fp4 e2m1 word (8 nibbles, LSB-first along K) -> 8 fp8 e4m3 bytes (k-order)
// Magnitude LUT (idx 0-7): 0x00,0x30,0x38,0x3C,0x40,0x44,0x48,0x4C; sign->bit7.
// 7 VALU per word.
// ---------------------------------------------------------------------------
__device__ __forceinline__ long dec8(uint32_t w) {
  uint32_t lo = w & 0x07070707u;          // mag idx n0,n2,n4,n6
  uint32_t hi = (w >> 4) & 0x07070707u;   // mag idx n1,n3,n5,n7
  uint32_t me = __builtin_amdgcn_perm(0x4C484440u, 0x3C383000u, lo);
  uint32_t mo = __builtin_amdgcn_perm(0x4C484440u, 0x3C383000u, hi);
  uint32_t e  = me | ((w & 0x08080808u) << 4);   // even nibbles + sign
  uint32_t o  = mo | (w & 0x80808080u);          // odd nibbles + sign
  uint32_t d0 = __builtin_amdgcn_perm(o, e, 0x05010400u);  // n0,n1,n2,n3
  uint32_t d1 = __builtin_amdgcn_perm(o, e, 0x07030602u);  // n4,n5,n6,n7
  return (long)(((uint64_t)d1 << 32) | d0);
}

// ---------------------------------------------------------------------------
// K0: x f32 [32,4096] -> two fp8(e4m3) planes: xh = fp8(x), xl = fp8(x-xh).
// Two-term split keeps activation quantization error ~0.4%.
// ---------------------------------------------------------------------------
__global__ __launch_bounds__(256) void k_prep(const float* __restrict__ x,
                                              uint32_t* __restrict__ xh,
                                              uint32_t* __restrict__ xl) {
  const int t = blockIdx.x * 256 + threadIdx.x;   // 16384 threads, 8 elems each
  const float* p = x + t * 8;
  f32x4 v0 = *(const f32x4*)p;
  f32x4 v1 = *(const f32x4*)(p + 4);
  float f[8] = {v0[0], v0[1], v0[2], v0[3], v1[0], v1[1], v1[2], v1[3]};
  uint32_t h0 = 0, h1 = 0;
  h0 = __builtin_amdgcn_cvt_pk_fp8_f32(f[0], f[1], h0, false);
  h0 = __builtin_amdgcn_cvt_pk_fp8_f32(f[2], f[3], h0, true);
  h1 = __builtin_amdgcn_cvt_pk_fp8_f32(f[4], f[5], h1, false);
  h1 = __builtin_amdgcn_cvt_pk_fp8_f32(f[6], f[7], h1, true);
  float r[8];
  r[0] = f[0] - __builtin_amdgcn_cvt_f32_fp8(h0, 0);
  r[1] = f[1] - __builtin_amdgcn_cvt_f32_fp8(h0, 1);
  r[2] = f[2] - __builtin_amdgcn_cvt_f32_fp8(h0, 2);
  r[3] = f[3] - __builtin_amdgcn_cvt_f32_fp8(h0, 3);
  r[4] = f[4] - __builtin_amdgcn_cvt_f32_fp8(h1, 0);
  r[5] = f[5] - __builtin_amdgcn_cvt_f32_fp8(h1, 1);
  r[6] = f[6] - __builtin_amdgcn_cvt_f32_fp8(h1, 2);
  r[7] = f[7] - __builtin_amdgcn_cvt_f32_fp8(h1, 3);
  uint32_t l0 = 0, l1 = 0;
  l0 = __builtin_amdgcn_cvt_pk_fp8_f32(r[0], r[1], l0, false);
  l0 = __builtin_amdgcn_cvt_pk_fp8_f32(r[2], r[3], l0, true);
  l1 = __builtin_amdgcn_cvt_pk_fp8_f32(r[4], r[5], l1, false);
  l1 = __builtin_amdgcn_cvt_pk_fp8_f32(r[6], r[7], l1, true);
  xh[t*2] = h0; xh[t*2+1] = h1;
  xl[t*2] = l0; xl[t*2+1] = l1;
}

// ---------------------------------------------------------------------------
// K1 (fused gate_up GEMM + SwiGLU): for act-col tile [c0, c0+16):
//   g[32x16] = x @ Wgu[:, c0:c0+16], u[32x16] = x @ Wgu[:, 2048+c0:...]
//   act = silu(g)*u -> two fp8 planes, written directly.
// 128 wgs x 1024 thr. 16 waves = K-chunk(256) each = 2 scale groups; per
// group: 4 K32 MFMA steps (hi+lo planes, 2 row-tiles, gate+up cols) into
// temps, then acc += scale*temp (exact). 16-way LDS reduce, swiglu epilogue.
// Layouts: A[m=lane&15][k=q*8+j]; B[k=q*8+j][n=lane&15]; C col=r,row=q*4+reg.
// ---------------------------------------------------------------------------
__global__ __launch_bounds__(1024, 4) void k_fused(
    const uint8_t* __restrict__ xh, const uint8_t* __restrict__ xl,
    const uint32_t* __restrict__ wp, const float* __restrict__ sc,
    uint8_t* __restrict__ a8h, uint8_t* __restrict__ a8l) {
  __shared__ float ldsg[16 * 512];
  __shared__ float ldsu[16 * 512];
  const int c0 = blockIdx.x * 16;          // act-col tile (0..2032)
  const int wid = threadIdx.x >> 6, lane = threadIdx.x & 63;
  const int q = lane >> 4, r = lane & 15;
  const int ng = c0 + r;                   // gate col
  const int nu = Iv + c0 + r;              // up col

  const int koff = wid * 256 + q * 8;      // fp8-elem offset in K
  const uint8_t* pa0h = xh + r * Hv + koff;
  const uint8_t* pa0l = xl + r * Hv + koff;
  const uint8_t* pa1h = xh + (r + 16) * Hv + koff;
  const uint8_t* pa1l = xl + (r + 16) * Hv + koff;
  // word row for K-step st (of 8): wid*32 + st*4 + q
  const uint32_t* pbg = wp + (size_t)(wid * 32 + q) * N1 + ng;
  const uint32_t* pbu = wp + (size_t)(wid * 32 + q) * N1 + nu;

  f32x4 ag0 = {0,0,0,0}, ag1 = {0,0,0,0}, au0 = {0,0,0,0}, au1 = {0,0,0,0};

  #pragma unroll
  for (int g = 0; g < 2; ++g) {            // 2 scale groups per wave
    f32x4 tg0 = {0,0,0,0}, tg1 = {0,0,0,0}, tu0 = {0,0,0,0}, tu1 = {0,0,0,0};
    #pragma unroll
    for (int st = 0; st < 4; ++st) {       // 4 x K=32 steps = one group
      const int ke = g * 128 + st * 32;    // elem offset within wave chunk
      const size_t kw = (size_t)(g * 16 + st * 4) * N1;  // word-row offset
      long A0h = *(const long*)(pa0h + ke);
      long A0l = *(const long*)(pa0l + ke);
      long A1h = *(const long*)(pa1h + ke);
      long A1l = *(const long*)(pa1l + ke);
      long Bg = dec8(pbg[kw]);
      long Bu = dec8(pbu[kw]);
      tg0 = __builtin_amdgcn_mfma_f32_16x16x32_fp8_fp8(A0h, Bg, tg0, 0, 0, 0);
      tg0 = __builtin_amdgcn_mfma_f32_16x16x32_fp8_fp8(A0l, Bg, tg0, 0, 0, 0);
      tg1 = __builtin_amdgcn_mfma_f32_16x16x32_fp8_fp8(A1h, Bg, tg1, 0, 0, 0);
      tg1 = __builtin_amdgcn_mfma_f32_16x16x32_fp8_fp8(A1l, Bg, tg1, 0, 0, 0);
      tu0 = __builtin_amdgcn_mfma_f32_16x16x32_fp8_fp8(A0h, Bu, tu0, 0, 0, 0);
      tu0 = __builtin_amdgcn_mfma_f32_16x16x32_fp8_fp8(A0l, Bu, tu0, 0, 0, 0);
      tu1 = __builtin_amdgcn_mfma_f32_16x16x32_fp8_fp8(A1h, Bu, tu1, 0, 0, 0);
      tu1 = __builtin_amdgcn_mfma_f32_16x16x32_fp8_fp8(A1l, Bu, tu1, 0, 0, 0);
    }
    const int grp = wid * 2 + g;           // scale group index (0..31)
    const float sg = sc[grp * N1 + ng];
    const float su = sc[grp * N1 + nu];
    #pragma unroll
    for (int j = 0; j < 4; ++j) {
      ag0[j] = fmaf(sg, tg0[j], ag0[j]);
      ag1[j] = fmaf(sg, tg1[j], ag1[j]);
      au0[j] = fmaf(su, tu0[j], au0[j]);
      au1[j] = fmaf(su, tu1[j], au1[j]);
    }
  }
  float* mg = ldsg + wid * 512;
  float* mu = ldsu + wid * 512;
  #pragma unroll
  for (int j = 0; j < 4; ++j) {
    const int rw = q * 4 + j;
    mg[rw * 16 + r]        = ag0[j];
    mg[(16 + rw) * 16 + r] = ag1[j];
    mu[rw * 16 + r]        = au0[j];
    mu[(16 + rw) * 16 + r] = au1[j];
  }
  __syncthreads();
  const int i = threadIdx.x;
  if (i < 512) {                           // 512 outputs: row=i>>4, col=i&15
    float gv = 0.f, uv = 0.f;
    #pragma unroll
    for (int w = 0; w < 16; ++w) {
      gv += ldsg[w * 512 + i];
      uv += ldsu[w * 512 + i];
    }
    float av = gv / (1.0f + __expf(-gv)) * uv;
    av = fminf(fmaxf(av, -440.0f), 440.0f);      // e4m3 NaN armor
    uint32_t hb = __builtin_amdgcn_cvt_pk_fp8_f32(av, av, 0, false);
    float rv = av - __builtin_amdgcn_cvt_f32_fp8(hb, 0);
    uint32_t lb = __builtin_amdgcn_cvt_pk_fp8_f32(rv, rv, 0, false);
    const int off = (i >> 4) * Iv + c0 + (i & 15);
    a8h[off] = (uint8_t)(hb & 0xFF);
    a8l[off] = (uint8_t)(lb & 0xFF);
  }
}

// ---------------------------------------------------------------------------
// K2: out f32 [32][4096] = act[32,2048] @ dequant(W_down).
// 256 wgs x 1024 thr: wg = 16-col tile x full K(2048). 16 waves = one scale
// group each; both row-tiles per wave; 16-way LDS reduce; direct f32 out.
// ---------------------------------------------------------------------------
__global__ __launch_bounds__(1024, 4) void k_down(
    const uint8_t* __restrict__ ah8, const uint8_t* __restrict__ al8,
    const uint32_t* __restrict__ wp, const float* __restrict__ sc,
    float* __restrict__ out) {
  __shared__ float lds[16 * 512];
  const int n0 = blockIdx.x * 16;
  const int wid = threadIdx.x >> 6, lane = threadIdx.x & 63;
  const int q = lane >> 4, r = lane & 15;
  const int n = n0 + r;

  const int koff = wid * 128 + q * 8;
  const uint8_t* pa0h = ah8 + r * Iv + koff;
  const uint8_t* pa0l = al8 + r * Iv + koff;
  const uint8_t* pa1h = ah8 + (r + 16) * Iv + koff;
  const uint8_t* pa1l = al8 + (r + 16) * Iv + koff;
  const uint32_t* pb = wp + (size_t)(wid * 16 + q) * Hv + n;

  f32x4 t0 = {0,0,0,0}, t1 = {0,0,0,0};
  #pragma unroll
  for (int st = 0; st < 4; ++st) {
    long A0h = *(const long*)(pa0h + st * 32);
    long A0l = *(const long*)(pa0l + st * 32);
    long A1h = *(const long*)(pa1h + st * 32);
    long A1l = *(const long*)(pa1l + st * 32);
    long Bf = dec8(pb[(size_t)st * 4 * Hv]);
    t0 = __builtin_amdgcn_mfma_f32_16x16x32_fp8_fp8(A0h, Bf, t0, 0, 0, 0);
    t0 = __builtin_amdgcn_mfma_f32_16x16x32_fp8_fp8(A0l, Bf, t0, 0, 0, 0);
    t1 = __builtin_amdgcn_mfma_f32_16x16x32_fp8_fp8(A1h, Bf, t1, 0, 0, 0);
    t1 = __builtin_amdgcn_mfma_f32_16x16x32_fp8_fp8(A1l, Bf, t1, 0, 0, 0);
  }
  const float sv = sc[wid * Hv + n];
  float* my = lds + wid * 512;
  #pragma unroll
  for (int j = 0; j < 4; ++j) {
    const int rw = q * 4 + j;
    my[rw * 16 + r]        = sv * t0[j];
    my[(16 + rw) * 16 + r] = sv * t1[j];
  }
  __syncthreads();
  const int i = threadIdx.x;
  if (i < 512) {                            // 512 outputs (32x16)
    float sum = 0.f;
    #pragma unroll
    for (int w = 0; w < 16; ++w) sum += lds[w * 512 + i];
    out[(i >> 4) * N1 + n0 + (i & 15)] = sum;
  }
}

// ---------------------------------------------------------------------------
extern "C" void kernel_launch(void* const* d_in, const int* in_sizes, int n_in,
                              void* d_out, int out_size, void* d_ws, size_t ws_size,
                              hipStream_t stream) {
  // Harness promotes float16 tensors to float32. x, scales, out are f32.
  const float*    x   = (const float*)d_in[0];      // f32 [32,4096]
  const uint32_t* gup = (const uint32_t*)d_in[1];   // [512,4096] packed fp4
  const float*    gus = (const float*)d_in[2];      // f32 [32,4096]
  const uint32_t* dnp = (const uint32_t*)d_in[3];   // [256,4096] packed fp4
  const float*    dns = (const float*)d_in[4];      // f32 [16,4096]

  uint8_t*  xh  = (uint8_t*)d_ws;                   // 128 KiB
  uint8_t*  xl  = xh + Bv*Hv;                       // 128 KiB
  uint8_t*  a8h = xl + Bv*Hv;                       // 64 KiB
  uint8_t*  a8l = a8h + Bv*Iv;                      // 64 KiB

  k_prep <<< 64,  256, 0, stream>>>(x, (uint32_t*)xh, (uint32_t*)xl);
  k_fused<<<128, 1024, 0, stream>>>(xh, xl, gup, gus, a8h, a8l);
  k_down <<<256, 1024, 0, stream>>>(a8h, a8l, dnp, dns, (float*)d_out);
}